// Round 6
// baseline (254.164 us; speedup 1.0000x reference)
//
#include <hip/hip_runtime.h>

// EWMA scan z_t = lam*z_{t-1} + (1-lam)*x_t over [B,L,K], chunk-parallel with
// 128-step warm-up (error <= lam^129 * max|z| ~ 1e-3 << 1.7e-2 threshold).
//
// R4:  CHUNK 32, float4, 16 w/CU -> 3.4 TB/s DRAM but 2.3x read traffic.
// R5-R8 NEUTRAL: K-split dword path, depth by construction, nt-vs-plain ->
//     all 2.7-2.8 TB/s DRAM.
// KEY RE-ANALYSIS (R8 post-mortem): count WAVE-VISIBLE bytes (warm re-reads
//     are cache-served; FETCH stays 130 MB at 254 MB logical). Wave-visible:
//     R0 4.2 (1KB reqs, no depth), R5/R7/R8 4.1 (depth, 256B reqs),
//     R4 6.0 TB/s (1KB reqs AND depth) == copy-ubench rate. The service rate
//     needs BOTH 16B/lane requests AND deep posted concurrency.
// R9: width x depth with 1x traffic: CHUNK=128, full-K wave (float4 layout,
//     1KB requests), depth via LDS-DMA ring at size=16 (global_load_lds
//     _dwordx4): 32-slot ring, 1 step = 1 KB = 1 DMA instr, prefetch
//     distance 31 -> ~30KB posted reads/wave x 4 waves/CU = 120 KB/CU.
//     Hand vmcnt (exact): steady vmcnt(60), ramp/tail vmcnt(30). No
//     barriers (ring wave-private). 256 blocks x 256 thr, LDS 128 KB/block.
//
// vmcnt derivation (1 load + 1 store instr per step, issue order
// [store(t); load(t+31)] inside step t; prologue posts loads 0..30):
//   steady (t in [warm+32, total-31]): younger-than-load(t) =
//     30 loads(t+1..t+30) + 30 stores(t-30..t-1) = 60 -> vmcnt(60) exact.
//   ramp (t < warm+32): stores absent/partial -> 30 loads younger;
//     vmcnt(30) exact at t=0, conservatively over-drains during store ramp.
//   tail (t > total-31): no loads left; 30 stores younger at t=total-1 ->
//     vmcnt(30) exact there, over-drains slightly before.
//   Max outstanding just before a wait: 61 <= 63 HW cap.

#define LAM  0.95f
#define CHUNK 128
#define WARM  128
#define RING  32      // power of 2: slot = t & 31

typedef float v4f __attribute__((ext_vector_type(4)));
typedef const __attribute__((address_space(1))) unsigned int gu32;
typedef __attribute__((address_space(3)))       unsigned int lu32;

constexpr int B = 16;
constexpr int L = 8192;
constexpr int K = 256;
constexpr int G = L / CHUNK;    // 64 chunks per batch
constexpr int S4 = K / 4;       // 64 float4 per time step

#define WAITV(N)                                                   \
    do {                                                           \
        asm volatile("s_waitcnt vmcnt(" #N ")" ::: "memory");      \
        __builtin_amdgcn_sched_barrier(0);                         \
    } while (0)

__global__ __launch_bounds__(256) void ewma_kernel(const float* __restrict__ x,
                                                   float* __restrict__ out) {
    __shared__ float lds[4][RING][K];             // 128 KB: [wave][slot][chan]

    const int wib  = (int)(threadIdx.x >> 6);     // wave index in block
    const int lane = threadIdx.x & 63;
    const int gw   = (int)(blockIdx.x * 4u) + wib;  // global wave task 0..1023
    const int b    = gw >> 6;                     // batch
    const int j    = gw & (G - 1);                // chunk index
    const int s    = j * CHUNK;                   // stored-region start
    const int t0   = (j == 0) ? 0 : (s - WARM);   // scan start (warm-up)

    const int total = (s + CHUNK) - t0;           // 128 (chunk 0) or 256
    const int warm  = s - t0;                     // 0 or 128

    const float* __restrict__ prow = x + (long)b * L * K + (long)t0 * K;
    v4f* __restrict__ pout = (v4f*)(out + (long)b * L * K + (long)lane * 4)
                             + (long)t0 * S4;

    const float c = 1.0f - LAM;
    v4f z = {0.f, 0.f, 0.f, 0.f};

    // One DMA instruction stages one full 1 KB time step: lane l supplies
    // bytes [l*16, l*16+16) of the row; HW scatters to ldsbase + l*16.
    auto stage = [&](int t) {
        const float* src = prow + (long)t * K + lane * 4;
        lu32* dst = (lu32*)&lds[wib][t & (RING - 1)][0];   // wave-uniform, 1KB-aligned
        __builtin_amdgcn_global_load_lds((gu32*)src, dst, 16, 0, 0);
    };

    // Consume one step: ds_read_b128 own 4 channels, 4 FMAs, full-line store.
    auto consume = [&](int t) {
        const v4f xv = *(const v4f*)&lds[wib][t & (RING - 1)][lane * 4];
        z.x = fmaf(LAM, z.x, c * xv.x);
        z.y = fmaf(LAM, z.y, c * xv.y);
        z.z = fmaf(LAM, z.z, c * xv.z);
        z.w = fmaf(LAM, z.w, c * xv.w);
        if (t >= warm) pout[(long)t * S4] = z;    // wave-uniform predicate
    };

    #pragma unroll 1
    for (int t = 0; t < RING - 1; ++t) stage(t);  // prologue: 31 loads posted

    const int s1e = warm + RING;                  // ramp end (32 or 160)
    const int s2e = total - RING + 1;             // steady end (97 or 225)

    int t = 0;
    #pragma unroll 1
    for (; t < s1e; ++t) {                        // ramp: vmcnt(30)
        WAITV(30);
        consume(t);
        stage(t + RING - 1);                      // t+31 < total always here
    }
    #pragma unroll 1
    for (; t < s2e; ++t) {                        // steady: vmcnt(60)
        WAITV(60);
        consume(t);
        stage(t + RING - 1);
    }
    #pragma unroll 1
    for (; t < total; ++t) {                      // tail: no loads remain
        WAITV(30);
        consume(t);
    }
}

extern "C" void kernel_launch(void* const* d_in, const int* in_sizes, int n_in,
                              void* d_out, int out_size, void* d_ws, size_t ws_size,
                              hipStream_t stream) {
    const float* x = (const float*)d_in[0];
    float* out = (float*)d_out;

    const int blocks = (B * G) / 4;      // 256 blocks x 256 threads, 1/CU
    hipLaunchKernelGGL(ewma_kernel, dim3(blocks), dim3(256), 0, stream, x, out);
}